// Round 9
// baseline (1478.773 us; speedup 1.0000x reference)
//
#include <hip/hip_runtime.h>
#include <hip/hip_cooperative_groups.h>

namespace cg = cooperative_groups;

#define NN    8192
#define NL    16
#define NE    (NN * 128)
#define NOUTC 16
#define EOUTC (NN * NOUTC)

#define NBLK  256
#define NTHR  1024
#define EPB   (NE / NBLK)        // 4096 edges per block per layer
#define OPB   (EOUTC / NBLK)     // 512 output edges per block

__device__ __forceinline__ float lrelu(float v) { return v >= 0.f ? v : 0.01f * v; }

__global__ __launch_bounds__(NTHR) void mega_kernel(
    const float* __restrict__ x,
    const float* __restrict__ edge_w,
    const float* __restrict__ out_w,
    const int*   __restrict__ edge_src,
    const int*   __restrict__ edge_dst,
    const int*   __restrict__ out_src,
    const int*   __restrict__ out_dst,
    float*       __restrict__ raw,    // [NL][NN] per-layer accumulators
    float*       __restrict__ outs,   // [NBLK][NOUTC]
    float*       __restrict__ out)    // [NOUTC]
{
    cg::grid_group grid = cg::this_grid();
    __shared__ float vals[NN];                 // 32 KB activated source vector
    __shared__ float bins[NOUTC];
    __shared__ float red[NOUTC][NOUTC + 1];

    const int tid = threadIdx.x;
    const int b   = blockIdx.x;

    // ---- prefetch layer-0 edge quads (read-only inputs: no hazards) ----
    const size_t e0 = (size_t)b * EPB + (size_t)tid * 4;
    int4   s4 = *(const int4*)(edge_src + e0);
    int4   d4 = *(const int4*)(edge_dst + e0);
    float4 w4 = *(const float4*)(edge_w + e0);

    // ---- zero all per-layer raw accumulators (ws may be poisoned) ----
    {
        const int g = b * NTHR + tid;          // 0..262143, NL*NN = 131072
        if (g < NL * NN) raw[g] = 0.f;
    }
    // ---- stage input vector (no lrelu on inputs) ----
    for (int i = tid * 4; i < NN; i += NTHR * 4)
        *(float4*)(vals + i) = *(const float4*)(x + i);

    grid.sync();   // raw[] zeroed device-wide; vals staged (subsumes __syncthreads)

    for (int l = 0; l < NL; ++l) {
        float* r = raw + (size_t)l * NN;

        // gather (LDS) -> fire-and-forget device-scope atomic scatter
        const float cx = vals[s4.x] * w4.x;
        const float cy = vals[s4.y] * w4.y;
        const float cz = vals[s4.z] * w4.z;
        const float cw = vals[s4.w] * w4.w;
        atomicAdd(r + d4.x, cx);
        atomicAdd(r + d4.y, cy);
        atomicAdd(r + d4.z, cz);
        atomicAdd(r + d4.w, cw);

        // prefetch next layer's edges BEFORE the barrier (hides HBM latency)
        if (l + 1 < NL) {
            const size_t e = (size_t)(l + 1) * NE + (size_t)b * EPB + (size_t)tid * 4;
            s4 = *(const int4*)(edge_src + e);
            d4 = *(const int4*)(edge_dst + e);
            w4 = *(const float4*)(edge_w + e);
        }

        grid.sync();   // raw[l] complete device-wide (release/acquire)

        // vals = lrelu(raw[l])  -- 32 KB broadcast read, L2/L3-resident
        for (int i = tid * 4; i < NN; i += NTHR * 4) {
            float4 v = *(const float4*)(r + i);
            v.x = lrelu(v.x); v.y = lrelu(v.y);
            v.z = lrelu(v.z); v.w = lrelu(v.w);
            *(float4*)(vals + i) = v;
        }
        __syncthreads();   // vals ready for next layer's gathers
    }

    // ---- output layer: 512 edges/block into 16 LDS bins ----
    if (tid < NOUTC) bins[tid] = 0.f;
    __syncthreads();
    if (tid < OPB) {
        const int e = b * OPB + tid;
        atomicAdd(&bins[out_dst[e]], vals[out_src[e]] * out_w[e]);
    }
    __syncthreads();
    if (tid < NOUTC) outs[(size_t)b * NOUTC + tid] = bins[tid];
    grid.sync();

    // ---- final: reduce 256x16, lrelu, softmax (block 0 only; no more syncs) ----
    if (b == 0) {
        if (tid < 256) {
            const int j = tid & 15, g = tid >> 4;
            float s = 0.f;
            #pragma unroll
            for (int r2 = 0; r2 < NBLK / 16; ++r2)
                s += outs[(size_t)(g + r2 * 16) * NOUTC + j];
            red[g][j] = s;
        }
        __syncthreads();
        if (tid < NOUTC) {
            float t = 0.f;
            #pragma unroll
            for (int g2 = 0; g2 < 16; ++g2) t += red[g2][tid];
            float v = lrelu(t);
            float m = v;
            #pragma unroll
            for (int off = 8; off >= 1; off >>= 1)
                m = fmaxf(m, __shfl_xor(m, off, 64));
            const float e = __expf(v - m);
            float ss = e;
            #pragma unroll
            for (int off = 8; off >= 1; off >>= 1)
                ss += __shfl_xor(ss, off, 64);
            out[tid] = e / ss;
        }
    }
}

extern "C" void kernel_launch(void* const* d_in, const int* in_sizes, int n_in,
                              void* d_out, int out_size, void* d_ws, size_t ws_size,
                              hipStream_t stream) {
    const float* x        = (const float*)d_in[0];
    const float* edge_w   = (const float*)d_in[1];
    const float* out_w    = (const float*)d_in[2];
    const int*   edge_src = (const int*)d_in[3];
    const int*   edge_dst = (const int*)d_in[4];
    const int*   out_src  = (const int*)d_in[5];
    const int*   out_dst  = (const int*)d_in[6];

    float* raw  = (float*)d_ws;                 // NL*NN floats (512 KB)
    float* outs = raw + (size_t)NL * NN;        // NBLK*NOUTC floats
    float* out  = (float*)d_out;

    void* args[] = {&x, &edge_w, &out_w, &edge_src, &edge_dst,
                    &out_src, &out_dst, &raw, &outs, &out};
    hipLaunchCooperativeKernel((void*)mega_kernel, dim3(NBLK), dim3(NTHR),
                               args, 0, stream);
}

// Round 10
// 1299.358 us; speedup vs baseline: 1.1381x; 1.1381x over previous
//
#include <hip/hip_runtime.h>
#include <hip/hip_cooperative_groups.h>

namespace cg = cooperative_groups;

#define NN    8192
#define NL    16
#define NE    (NN * 128)
#define NOUTC 16
#define EOUTC (NN * NOUTC)

#define NBLK  256
#define NTHR  1024
#define EPB   (NE / NBLK)        // 4096 edges per block per layer == NTHR*4
#define NPB   (NN / NBLK)        // 32 neurons owned per block in reduce
#define OPB   (EOUTC / NBLK)     // 512 output edges per block

__device__ __forceinline__ float lrelu(float v) { return v >= 0.f ? v : 0.01f * v; }

__global__ __launch_bounds__(NTHR) void mega_kernel(
    const float* __restrict__ x,
    const float* __restrict__ edge_w,
    const float* __restrict__ out_w,
    const int*   __restrict__ edge_src,
    const int*   __restrict__ edge_dst,
    const int*   __restrict__ out_src,
    const int*   __restrict__ out_dst,
    float*       __restrict__ partials, // [NBLK][NN] (8 MB, L2-resident)
    float*       __restrict__ accv,     // [NL][NN] activated layer vectors
    float*       __restrict__ outs,     // [NBLK][NOUTC]
    float*       __restrict__ out)      // [NOUTC]
{
    cg::grid_group grid = cg::this_grid();
    __shared__ float vals[NN];          // 32 KB activated source vector
    __shared__ float accs[NN];          // 32 KB private accumulator
    __shared__ float sred[32][33];      // reduce scratch (pad: conflict-free)
    __shared__ float bins[NOUTC];
    __shared__ float red[NOUTC][NOUTC + 1];

    const int tid = threadIdx.x;
    const int b   = blockIdx.x;

    // ---- stage input vector into LDS (block-local; no grid sync needed) ----
    for (int i = tid * 4; i < NN; i += NTHR * 4)
        *(float4*)(vals + i) = *(const float4*)(x + i);

    // ---- prefetch layer-0 edge quads into registers ----
    const size_t e0 = (size_t)b * EPB + (size_t)tid * 4;
    int4   s4 = *(const int4*)(edge_src + e0);
    int4   d4 = *(const int4*)(edge_dst + e0);
    float4 w4 = *(const float4*)(edge_w + e0);

    float* const prow = partials + (size_t)b * NN;

    for (int l = 0; l < NL; ++l) {
        // zero private accumulator; barrier also covers vals staging above
        for (int i = tid * 4; i < NN; i += NTHR * 4)
            *(float4*)(accs + i) = make_float4(0.f, 0.f, 0.f, 0.f);
        __syncthreads();

        // ---- scatter: gather from LDS vals, accumulate via LDS atomics ----
        atomicAdd(&accs[d4.x], vals[s4.x] * w4.x);
        atomicAdd(&accs[d4.y], vals[s4.y] * w4.y);
        atomicAdd(&accs[d4.z], vals[s4.z] * w4.z);
        atomicAdd(&accs[d4.w], vals[s4.w] * w4.w);

        // prefetch next layer's edge quads (HBM latency hides under barrier+write)
        if (l + 1 < NL) {
            const size_t e = (size_t)(l + 1) * NE + (size_t)b * EPB + (size_t)tid * 4;
            s4 = *(const int4*)(edge_src + e);
            d4 = *(const int4*)(edge_dst + e);
            w4 = *(const float4*)(edge_w + e);
        }
        __syncthreads();   // all LDS atomics done

        // ---- coalesced dense partial-row write (stays hot in L2) ----
        for (int i = tid * 4; i < NN; i += NTHR * 4)
            *(float4*)(prow + i) = *(const float4*)(accs + i);

        grid.sync();       // sync 1: all partial rows visible device-wide

        // ---- reduce: block owns neurons [b*32, b*32+32) ----
        {
            const int nl = tid & 31;     // neuron within slice
            const int kg = tid >> 5;     // 0..31 row-groups
            const int n  = b * NPB + nl;
            float s = 0.f;
            #pragma unroll
            for (int k = 0; k < 8; ++k)
                s += partials[(size_t)(kg * 8 + k) * NN + n];
            sred[kg][nl] = s;
            __syncthreads();
            if (tid < 32) {
                float t = 0.f;
                #pragma unroll
                for (int j = 0; j < 32; ++j) t += sred[j][tid];
                accv[(size_t)l * NN + b * NPB + tid] = lrelu(t);
            }
        }

        grid.sync();       // sync 2: accv[l] complete device-wide

        // ---- reload activated vector into LDS for next layer ----
        const float* src = accv + (size_t)l * NN;
        for (int i = tid * 4; i < NN; i += NTHR * 4)
            *(float4*)(vals + i) = *(const float4*)(src + i);
        // next iteration's zero-loop __syncthreads covers this staging
    }

    // ---- output layer: 512 edges/block into 16 LDS bins ----
    __syncthreads();       // vals (layer-15 activations) ready in LDS
    if (tid < NOUTC) bins[tid] = 0.f;
    __syncthreads();
    if (tid < OPB) {
        const int e = b * OPB + tid;
        atomicAdd(&bins[out_dst[e]], vals[out_src[e]] * out_w[e]);
    }
    __syncthreads();
    if (tid < NOUTC) outs[(size_t)b * NOUTC + tid] = bins[tid];
    grid.sync();           // sync 33: outs complete

    // ---- final: reduce 256x16, lrelu, softmax (block 0 only) ----
    if (b == 0) {
        if (tid < 256) {
            const int j = tid & 15, g = tid >> 4;
            float s = 0.f;
            #pragma unroll
            for (int r2 = 0; r2 < NBLK / 16; ++r2)
                s += outs[(size_t)(g + r2 * 16) * NOUTC + j];
            red[g][j] = s;
        }
        __syncthreads();
        if (tid < NOUTC) {
            float t = 0.f;
            #pragma unroll
            for (int g2 = 0; g2 < 16; ++g2) t += red[g2][tid];
            float v = lrelu(t);
            float m = v;
            #pragma unroll
            for (int off = 8; off >= 1; off >>= 1)
                m = fmaxf(m, __shfl_xor(m, off, 64));
            const float e = __expf(v - m);
            float ss = e;
            #pragma unroll
            for (int off = 8; off >= 1; off >>= 1)
                ss += __shfl_xor(ss, off, 64);
            out[tid] = e / ss;
        }
    }
}

extern "C" void kernel_launch(void* const* d_in, const int* in_sizes, int n_in,
                              void* d_out, int out_size, void* d_ws, size_t ws_size,
                              hipStream_t stream) {
    const float* x        = (const float*)d_in[0];
    const float* edge_w   = (const float*)d_in[1];
    const float* out_w    = (const float*)d_in[2];
    const int*   edge_src = (const int*)d_in[3];
    const int*   edge_dst = (const int*)d_in[4];
    const int*   out_src  = (const int*)d_in[5];
    const int*   out_dst  = (const int*)d_in[6];

    float* partials = (float*)d_ws;                       // NBLK*NN floats (8 MB)
    float* accv     = partials + (size_t)NBLK * NN;       // NL*NN floats (512 KB)
    float* outs     = accv + (size_t)NL * NN;             // NBLK*NOUTC floats
    float* out      = (float*)d_out;

    void* args[] = {&x, &edge_w, &out_w, &edge_src, &edge_dst,
                    &out_src, &out_dst, &partials, &accv, &outs, &out};
    hipLaunchCooperativeKernel((void*)mega_kernel, dim3(NBLK), dim3(NTHR),
                               args, 0, stream);
}

// Round 12
// 1047.708 us; speedup vs baseline: 1.4114x; 1.2402x over previous
//
#include <hip/hip_runtime.h>
#include <hip/hip_cooperative_groups.h>

#define NN    8192
#define NL    16
#define NE    (NN * 128)
#define NOUTC 16
#define EOUTC (NN * NOUTC)

#define NBLK  256
#define NTHR  1024
#define EPB   (NE / NBLK)        // 4096 edges per block per layer == NTHR*4
#define NPB   (NN / NBLK)        // 32 neurons owned per block in reduce
#define OPB   (EOUTC / NBLK)     // 512 output edges per block
#define NBAR  64                 // barrier sites (33 used per invocation)

__device__ __forceinline__ float lrelu(float v) { return v >= 0.f ? v : 0.01f * v; }

// Monotonic grid barrier counters. __device__ globals are zero-initialized at
// module load and NOT poisoned by the harness (it poisons d_ws only).
// Monotonic generations => no reset protocol; safe across bench iterations
// and rocprof replays (2^32/NBLK = 16.7M uses per site).
__device__ unsigned g_bar[NBAR];

__device__ __forceinline__ void grid_barrier(int idx) {
    __syncthreads();                        // all block work done (waitcnt+barrier)
    if (threadIdx.x == 0) {
        __threadfence();                    // release: flush block's writes device-wide
        unsigned old = __hip_atomic_fetch_add(&g_bar[idx], 1u,
                           __ATOMIC_RELEASE, __HIP_MEMORY_SCOPE_AGENT);
        unsigned target = (old / NBLK + 1u) * NBLK;   // end of my generation
        while (__hip_atomic_load(&g_bar[idx], __ATOMIC_RELAXED,
                                 __HIP_MEMORY_SCOPE_AGENT) < target)
            __builtin_amdgcn_s_sleep(2);
        __threadfence();                    // acquire: invalidate stale cached data
    }
    __syncthreads();                        // release whole block
}

__global__ __launch_bounds__(NTHR) void mega_kernel(
    const float* __restrict__ x,
    const float* __restrict__ edge_w,
    const float* __restrict__ out_w,
    const int*   __restrict__ edge_src,
    const int*   __restrict__ edge_dst,
    const int*   __restrict__ out_src,
    const int*   __restrict__ out_dst,
    float*       __restrict__ partials, // [NBLK][NN] (8 MB)
    float*       __restrict__ accv,     // [NN] activated layer vector
    float*       __restrict__ outs,     // [NBLK][NOUTC]
    float*       __restrict__ out)      // [NOUTC]
{
    __shared__ float vals[NN];          // 32 KB activated source vector
    __shared__ float accs[NN];          // 32 KB private accumulator
    __shared__ float sred[32][33];      // reduce scratch (padded)
    __shared__ float bins[NOUTC];
    __shared__ float red[NOUTC][NOUTC + 1];

    const int tid = threadIdx.x;
    const int b   = blockIdx.x;

    // ---- stage input vector into LDS (block-local) ----
    for (int i = tid * 4; i < NN; i += NTHR * 4)
        *(float4*)(vals + i) = *(const float4*)(x + i);

    // ---- prefetch layer-0 edge quads into registers ----
    const size_t e0 = (size_t)b * EPB + (size_t)tid * 4;
    int4   s4 = *(const int4*)(edge_src + e0);
    int4   d4 = *(const int4*)(edge_dst + e0);
    float4 w4 = *(const float4*)(edge_w + e0);

    float* const prow = partials + (size_t)b * NN;

    for (int l = 0; l < NL; ++l) {
        // zero private accumulator; barrier also covers vals staging
        for (int i = tid * 4; i < NN; i += NTHR * 4)
            *(float4*)(accs + i) = make_float4(0.f, 0.f, 0.f, 0.f);
        __syncthreads();

        // ---- scatter: gather from LDS vals, accumulate via LDS atomics ----
        atomicAdd(&accs[d4.x], vals[s4.x] * w4.x);
        atomicAdd(&accs[d4.y], vals[s4.y] * w4.y);
        atomicAdd(&accs[d4.z], vals[s4.z] * w4.z);
        atomicAdd(&accs[d4.w], vals[s4.w] * w4.w);

        // prefetch next layer's edge quads (latency hides under barrier+write)
        if (l + 1 < NL) {
            const size_t e = (size_t)(l + 1) * NE + (size_t)b * EPB + (size_t)tid * 4;
            s4 = *(const int4*)(edge_src + e);
            d4 = *(const int4*)(edge_dst + e);
            w4 = *(const float4*)(edge_w + e);
        }
        __syncthreads();   // all LDS atomics done

        // ---- coalesced dense partial-row write ----
        for (int i = tid * 4; i < NN; i += NTHR * 4)
            *(float4*)(prow + i) = *(const float4*)(accs + i);

        grid_barrier(2 * l);           // all partial rows visible device-wide

        // ---- reduce: block owns neurons [b*32, b*32+32) ----
        {
            const int nl = tid & 31;     // neuron within slice
            const int kg = tid >> 5;     // 0..31 row-groups
            const int n  = b * NPB + nl;
            float s = 0.f;
            #pragma unroll
            for (int k = 0; k < 8; ++k)
                s += partials[(size_t)(kg * 8 + k) * NN + n];
            sred[kg][nl] = s;
            __syncthreads();
            if (tid < 32) {
                float t = 0.f;
                #pragma unroll
                for (int j = 0; j < 32; ++j) t += sred[j][tid];
                accv[b * NPB + tid] = lrelu(t);
            }
        }

        grid_barrier(2 * l + 1);       // accv complete device-wide

        // ---- reload activated vector into LDS for next layer ----
        for (int i = tid * 4; i < NN; i += NTHR * 4)
            *(float4*)(vals + i) = *(const float4*)(accv + i);
        // next iteration's zero-loop __syncthreads covers this staging
    }

    // ---- output layer: 512 edges/block into 16 LDS bins ----
    __syncthreads();       // vals (layer-15 activations) ready in LDS
    if (tid < NOUTC) bins[tid] = 0.f;
    __syncthreads();
    if (tid < OPB) {
        const int e = b * OPB + tid;
        atomicAdd(&bins[out_dst[e]], vals[out_src[e]] * out_w[e]);
    }
    __syncthreads();
    if (tid < NOUTC) outs[(size_t)b * NOUTC + tid] = bins[tid];
    grid_barrier(32);      // outs complete device-wide

    // ---- final: reduce 256x16, lrelu, softmax (block 0 only) ----
    if (b == 0) {
        if (tid < 256) {
            const int j = tid & 15, g = tid >> 4;
            float s = 0.f;
            #pragma unroll
            for (int r2 = 0; r2 < NBLK / 16; ++r2)
                s += outs[(size_t)(g + r2 * 16) * NOUTC + j];
            red[g][j] = s;
        }
        __syncthreads();
        if (tid < NOUTC) {
            float t = 0.f;
            #pragma unroll
            for (int g2 = 0; g2 < 16; ++g2) t += red[g2][tid];
            float v = lrelu(t);
            float m = v;
            #pragma unroll
            for (int off = 8; off >= 1; off >>= 1)
                m = fmaxf(m, __shfl_xor(m, off, 64));
            const float e = __expf(v - m);
            float ss = e;
            #pragma unroll
            for (int off = 8; off >= 1; off >>= 1)
                ss += __shfl_xor(ss, off, 64);
            out[tid] = e / ss;
        }
    }
}

extern "C" void kernel_launch(void* const* d_in, const int* in_sizes, int n_in,
                              void* d_out, int out_size, void* d_ws, size_t ws_size,
                              hipStream_t stream) {
    const float* x        = (const float*)d_in[0];
    const float* edge_w   = (const float*)d_in[1];
    const float* out_w    = (const float*)d_in[2];
    const int*   edge_src = (const int*)d_in[3];
    const int*   edge_dst = (const int*)d_in[4];
    const int*   out_src  = (const int*)d_in[5];
    const int*   out_dst  = (const int*)d_in[6];

    float* partials = (float*)d_ws;                       // NBLK*NN floats (8 MB)
    float* accv     = partials + (size_t)NBLK * NN;       // NN floats
    float* outs     = accv + NN;                          // NBLK*NOUTC floats
    float* out      = (float*)d_out;

    void* args[] = {&x, &edge_w, &out_w, &edge_src, &edge_dst,
                    &out_src, &out_dst, &partials, &accv, &outs, &out};
    hipLaunchCooperativeKernel((void*)mega_kernel, dim3(NBLK), dim3(NTHR),
                               args, 0, stream);
}

// Round 15
// 605.442 us; speedup vs baseline: 2.4425x; 1.7305x over previous
//
#include <hip/hip_runtime.h>
#include <hip/hip_cooperative_groups.h>

typedef unsigned long long u64;

#define NN    8192
#define NL    16
#define NE    (NN * 128)
#define NOUTC 16
#define EOUTC (NN * NOUTC)

#define NBLK  256
#define NTHR  1024
#define EPB   (NE / NBLK)        // 4096 edges per block per layer == NTHR*4
#define NPB   (NN / NBLK)        // 32 neurons owned per block in reduce
#define OPB   (EOUTC / NBLK)     // 512 output edges per block
#define NBAR  64                 // barrier sites (33 used per invocation)

__device__ __forceinline__ float lrelu(float v) { return v >= 0.f ? v : 0.01f * v; }

// ---- agent-scope (SC1, L2-bypassing) data accessors ----------------------
// All cross-block buffers are accessed ONLY through these: data lives at the
// device coherence point (Infinity Cache), so no L2 writeback/invalidate
// fences are ever needed. __syncthreads() drains vmcnt -> stores visible.
__device__ __forceinline__ void st_f2(float* p, float a, float b) {
    u64 v = ((u64)__float_as_uint(b) << 32) | (u64)__float_as_uint(a);
    __hip_atomic_store((u64*)p, v, __ATOMIC_RELAXED, __HIP_MEMORY_SCOPE_AGENT);
}
__device__ __forceinline__ float2 ld_f2(const float* p) {
    u64 v = __hip_atomic_load((u64*)(uintptr_t)p, __ATOMIC_RELAXED,
                              __HIP_MEMORY_SCOPE_AGENT);
    return make_float2(__uint_as_float((unsigned)(v & 0xffffffffu)),
                       __uint_as_float((unsigned)(v >> 32)));
}
__device__ __forceinline__ void st_f(float* p, float a) {
    __hip_atomic_store((unsigned*)p, __float_as_uint(a),
                       __ATOMIC_RELAXED, __HIP_MEMORY_SCOPE_AGENT);
}
__device__ __forceinline__ float ld_f(const float* p) {
    unsigned v = __hip_atomic_load((unsigned*)(uintptr_t)p, __ATOMIC_RELAXED,
                                   __HIP_MEMORY_SCOPE_AGENT);
    return __uint_as_float(v);
}

// Monotonic grid barrier. __device__ globals zero-initialized at module load;
// generation counting => no reset protocol. Cooperative launch guarantees
// co-residency (all 256 blocks running) => every launch completes every
// barrier => counters stay multiples of NBLK => no torn-state deadlock.
// NO __threadfence(): all cross-block data is SC1-coherent; ordering comes
// from program order + the vmcnt drain in __syncthreads().
__device__ unsigned g_bar[NBAR];

__device__ __forceinline__ void grid_barrier(int idx) {
    __syncthreads();                 // drains vmcnt: sc1 stores at coherence pt
    if (threadIdx.x == 0) {
        unsigned old = __hip_atomic_fetch_add(&g_bar[idx], 1u,
                           __ATOMIC_RELAXED, __HIP_MEMORY_SCOPE_AGENT);
        unsigned target = (old / NBLK + 1u) * NBLK;   // end of my generation
        while (__hip_atomic_load(&g_bar[idx], __ATOMIC_RELAXED,
                                 __HIP_MEMORY_SCOPE_AGENT) < target)
            __builtin_amdgcn_s_sleep(1);
        asm volatile("" ::: "memory");               // no hoisting past poll
    }
    __syncthreads();
}

__global__ __launch_bounds__(NTHR) void mega_kernel(
    const float* __restrict__ x,
    const float* __restrict__ edge_w,
    const float* __restrict__ out_w,
    const int*   __restrict__ edge_src,
    const int*   __restrict__ edge_dst,
    const int*   __restrict__ out_src,
    const int*   __restrict__ out_dst,
    float*       __restrict__ partials, // [NBLK][NN] (8 MB, SC1/L3-resident)
    float*       __restrict__ accv,     // [NN] activated layer vector (SC1)
    float*       __restrict__ outs,     // [NBLK][NOUTC] (SC1)
    float*       __restrict__ out)      // [NOUTC]
{
    __shared__ float  vals[NN];          // 32 KB activated source vector
    __shared__ float  accs[NN];          // 32 KB private accumulator
    __shared__ float2 sred2[64][17];     // reduce scratch (padded)
    __shared__ float  bins[NOUTC];
    __shared__ float  red[NOUTC][NOUTC + 1];

    const int tid = threadIdx.x;
    const int b   = blockIdx.x;

    // ---- stage input vector into LDS (read-only input: plain loads) ----
    for (int i = tid * 4; i < NN; i += NTHR * 4)
        *(float4*)(vals + i) = *(const float4*)(x + i);

    // ---- prefetch layer-0 edge quads into registers (plain cached) ----
    const size_t e0 = (size_t)b * EPB + (size_t)tid * 4;
    int4   s4 = *(const int4*)(edge_src + e0);
    int4   d4 = *(const int4*)(edge_dst + e0);
    float4 w4 = *(const float4*)(edge_w + e0);

    float* const prow = partials + (size_t)b * NN;

    for (int l = 0; l < NL; ++l) {
        // zero private accumulator; barrier also covers vals staging
        for (int i = tid * 4; i < NN; i += NTHR * 4)
            *(float4*)(accs + i) = make_float4(0.f, 0.f, 0.f, 0.f);
        __syncthreads();

        // ---- scatter: gather from LDS vals, accumulate via LDS atomics ----
        atomicAdd(&accs[d4.x], vals[s4.x] * w4.x);
        atomicAdd(&accs[d4.y], vals[s4.y] * w4.y);
        atomicAdd(&accs[d4.z], vals[s4.z] * w4.z);
        atomicAdd(&accs[d4.w], vals[s4.w] * w4.w);

        // prefetch next layer's edge quads (latency hides under barrier)
        if (l + 1 < NL) {
            const size_t e = (size_t)(l + 1) * NE + (size_t)b * EPB + (size_t)tid * 4;
            s4 = *(const int4*)(edge_src + e);
            d4 = *(const int4*)(edge_dst + e);
            w4 = *(const float4*)(edge_w + e);
        }
        __syncthreads();   // all LDS atomics done

        // ---- partial-row write: 8 floats/thread via 4 SC1 float2 stores ----
        {
            const int i = tid * 8;   // NTHR*8 == NN exactly: one pass
            st_f2(prow + i,     accs[i],     accs[i + 1]);
            st_f2(prow + i + 2, accs[i + 2], accs[i + 3]);
            st_f2(prow + i + 4, accs[i + 4], accs[i + 5]);
            st_f2(prow + i + 6, accs[i + 6], accs[i + 7]);
        }

        grid_barrier(2 * l);           // all partial rows visible device-wide

        // ---- reduce: block owns neurons [b*32, b*32+32) ----
        {
            const int c2 = tid & 15;     // float2-column within slice (32 floats)
            const int rg = tid >> 4;     // 0..63 row-groups, 4 rows each
            const float* col = partials + (size_t)(b * NPB) + 2 * c2;
            float2 s = make_float2(0.f, 0.f);
            #pragma unroll
            for (int k = 0; k < 4; ++k) {
                float2 v = ld_f2(col + (size_t)(rg * 4 + k) * NN);
                s.x += v.x; s.y += v.y;
            }
            sred2[rg][c2] = s;
            __syncthreads();
            if (tid < 16) {
                float2 t = make_float2(0.f, 0.f);
                #pragma unroll
                for (int j = 0; j < 64; ++j) {
                    float2 v = sred2[j][tid];
                    t.x += v.x; t.y += v.y;
                }
                st_f2(accv + b * NPB + 2 * tid, lrelu(t.x), lrelu(t.y));
            }
        }

        grid_barrier(2 * l + 1);       // accv complete device-wide

        // ---- reload activated vector into LDS (SC1 loads; L2 may be stale) ----
        {
            const int i = tid * 8;
            float2 v0 = ld_f2(accv + i);
            float2 v1 = ld_f2(accv + i + 2);
            float2 v2 = ld_f2(accv + i + 4);
            float2 v3 = ld_f2(accv + i + 6);
            vals[i]     = v0.x; vals[i + 1] = v0.y;
            vals[i + 2] = v1.x; vals[i + 3] = v1.y;
            vals[i + 4] = v2.x; vals[i + 5] = v2.y;
            vals[i + 6] = v3.x; vals[i + 7] = v3.y;
        }
        // next iteration's zero-loop __syncthreads covers this staging
    }

    // ---- output layer: 512 edges/block into 16 LDS bins ----
    __syncthreads();       // vals (layer-15 activations) ready in LDS
    if (tid < NOUTC) bins[tid] = 0.f;
    __syncthreads();
    if (tid < OPB) {
        const int e = b * OPB + tid;
        atomicAdd(&bins[out_dst[e]], vals[out_src[e]] * out_w[e]);
    }
    __syncthreads();
    if (tid < NOUTC) st_f(outs + (size_t)b * NOUTC + tid, bins[tid]);
    grid_barrier(32);      // outs complete device-wide

    // ---- final: reduce 256x16, lrelu, softmax (block 0 only) ----
    if (b == 0) {
        if (tid < 256) {
            const int j = tid & 15, g = tid >> 4;
            float s = 0.f;
            #pragma unroll
            for (int r2 = 0; r2 < NBLK / 16; ++r2)
                s += ld_f(outs + (size_t)(g + r2 * 16) * NOUTC + j);
            red[g][j] = s;
        }
        __syncthreads();
        if (tid < NOUTC) {
            float t = 0.f;
            #pragma unroll
            for (int g2 = 0; g2 < 16; ++g2) t += red[g2][tid];
            float v = lrelu(t);
            float m = v;
            #pragma unroll
            for (int off = 8; off >= 1; off >>= 1)
                m = fmaxf(m, __shfl_xor(m, off, 64));
            const float e = __expf(v - m);
            float ss = e;
            #pragma unroll
            for (int off = 8; off >= 1; off >>= 1)
                ss += __shfl_xor(ss, off, 64);
            out[tid] = e / ss;
        }
    }
}

extern "C" void kernel_launch(void* const* d_in, const int* in_sizes, int n_in,
                              void* d_out, int out_size, void* d_ws, size_t ws_size,
                              hipStream_t stream) {
    const float* x        = (const float*)d_in[0];
    const float* edge_w   = (const float*)d_in[1];
    const float* out_w    = (const float*)d_in[2];
    const int*   edge_src = (const int*)d_in[3];
    const int*   edge_dst = (const int*)d_in[4];
    const int*   out_src  = (const int*)d_in[5];
    const int*   out_dst  = (const int*)d_in[6];

    float* partials = (float*)d_ws;                       // NBLK*NN floats (8 MB)
    float* accv     = partials + (size_t)NBLK * NN;       // NN floats
    float* outs     = accv + NN;                          // NBLK*NOUTC floats
    float* out      = (float*)d_out;

    void* args[] = {&x, &edge_w, &out_w, &edge_src, &edge_dst,
                    &out_src, &out_dst, &partials, &accv, &outs, &out};
    hipLaunchCooperativeKernel((void*)mega_kernel, dim3(NBLK), dim3(NTHR),
                               args, 0, stream);
}

// Round 21
// 425.758 us; speedup vs baseline: 3.4733x; 1.4220x over previous
//
#include <hip/hip_runtime.h>
#include <hip/hip_cooperative_groups.h>

typedef unsigned long long u64;
typedef float f32x4 __attribute__((ext_vector_type(4)));

#define NN    8192
#define NL    16
#define NE    (NN * 128)
#define NOUTC 16
#define EOUTC (NN * NOUTC)

#define NBLK  256
#define NTHR  1024
#define EPB   (NE / NBLK)        // 4096 edges per block per layer == NTHR*4
#define NPB   (NN / NBLK)        // 32 neurons owned per block in reduce
#define OPB   (EOUTC / NBLK)     // 512 output edges per block
#define NBAR  40                 // barrier sites (33 used per invocation)
#define NCTR  16                 // arrival counters per site (64B-padded)
#define GPC   (NBLK / NCTR)      // 16 arrivals per counter

__device__ __forceinline__ float lrelu(float v) { return v >= 0.f ? v : 0.01f * v; }

// ---- 16B SC1 (L2-bypassing, device-coherent) accessors via inline asm ----
// Cross-block data lives at the device coherence point; no cache fences ever.
__device__ __forceinline__ void st2_f4_sc(float* p0, f32x4 a, float* p1, f32x4 b) {
    asm volatile(
        "global_store_dwordx4 %0, %1, off sc0 sc1\n\t"
        "global_store_dwordx4 %2, %3, off sc0 sc1"
        :: "v"(p0), "v"(a), "v"(p1), "v"(b) : "memory");
}
__device__ __forceinline__ void st_f4_sc(float* p, f32x4 a) {
    asm volatile("global_store_dwordx4 %0, %1, off sc0 sc1"
                 :: "v"(p), "v"(a) : "memory");
}
__device__ __forceinline__ void ld2_f4_sc(const float* p0, const float* p1,
                                          f32x4& a, f32x4& b) {
    asm volatile(
        "global_load_dwordx4 %0, %2, off sc0 sc1\n\t"
        "global_load_dwordx4 %1, %3, off sc0 sc1\n\t"
        "s_waitcnt vmcnt(0)"
        : "=&v"(a), "=&v"(b) : "v"(p0), "v"(p1) : "memory");
}
__device__ __forceinline__ void st_f(float* p, float a) {
    __hip_atomic_store((unsigned*)p, __float_as_uint(a),
                       __ATOMIC_RELAXED, __HIP_MEMORY_SCOPE_AGENT);
}
__device__ __forceinline__ float ld_f(const float* p) {
    unsigned v = __hip_atomic_load((unsigned*)(uintptr_t)p, __ATOMIC_RELAXED,
                                   __HIP_MEMORY_SCOPE_AGENT);
    return __uint_as_float(v);
}

// ---- distributed-counter grid barrier (monotonic, no reset, no fences) ----
// 16 padded counters/site -> arrival adds are 16-way parallel (max 16-deep
// same-line serialization). Leader (block 0) waits for all counters, then
// publishes a go-flag; 255 blocks poll one line. Cooperative launch
// guarantees co-residency => no torn generations.
__device__ unsigned g_cnt[NBAR][NCTR][16];   // [site][counter][64B pad]
__device__ unsigned g_go[NBAR][16];          // [site][64B pad]

__device__ __forceinline__ void grid_barrier(int site) {
    // every wave drains its own vmem (incl. inline-asm SC1 stores the
    // compiler's pre-barrier waitcnt doesn't know about)
    asm volatile("s_waitcnt vmcnt(0)" ::: "memory");
    __syncthreads();
    if (threadIdx.x == 0) {
        const int c = blockIdx.x & (NCTR - 1);
        unsigned old = __hip_atomic_fetch_add(&g_cnt[site][c][0], 1u,
                           __ATOMIC_RELAXED, __HIP_MEMORY_SCOPE_AGENT);
        const unsigned epoch  = old / GPC;            // same for all this gen
        const unsigned target = (epoch + 1) * GPC;
        if (blockIdx.x == 0) {
            for (;;) {
                unsigned mn = 0xffffffffu;
                #pragma unroll
                for (int k = 0; k < NCTR; ++k) {
                    unsigned v = __hip_atomic_load(&g_cnt[site][k][0],
                                     __ATOMIC_RELAXED, __HIP_MEMORY_SCOPE_AGENT);
                    mn = mn < v ? mn : v;
                }
                if (mn >= target) break;
                __builtin_amdgcn_s_sleep(2);
            }
            __hip_atomic_fetch_add(&g_go[site][0], 1u,
                                   __ATOMIC_RELAXED, __HIP_MEMORY_SCOPE_AGENT);
        } else {
            while (__hip_atomic_load(&g_go[site][0], __ATOMIC_RELAXED,
                                     __HIP_MEMORY_SCOPE_AGENT) < epoch + 1)
                __builtin_amdgcn_s_sleep(2);
        }
        asm volatile("" ::: "memory");
    }
    __syncthreads();
}

__global__ __launch_bounds__(NTHR) void mega_kernel(
    const float* __restrict__ x,
    const float* __restrict__ edge_w,
    const float* __restrict__ out_w,
    const int*   __restrict__ edge_src,
    const int*   __restrict__ edge_dst,
    const int*   __restrict__ out_src,
    const int*   __restrict__ out_dst,
    float*       __restrict__ partials, // [NBLK][NN] (8 MB, SC1/L3-resident)
    float*       __restrict__ accv,     // [NN] activated layer vector (SC1)
    float*       __restrict__ outs,     // [NBLK][NOUTC] (SC1)
    float*       __restrict__ out)      // [NOUTC]
{
    __shared__ float vals[NN];           // 32 KB activated source vector
    __shared__ float accs[NN];           // 32 KB private accumulator
    __shared__ f32x4 sred4[128][9];      // reduce phase-1 scratch (padded)
    __shared__ f32x4 sredb[8][9];        // reduce phase-2 scratch
    __shared__ float bins[NOUTC];
    __shared__ float red[NOUTC][NOUTC + 1];

    const int tid = threadIdx.x;
    const int b   = blockIdx.x;

    // ---- stage input vector into LDS (read-only input: plain loads) ----
    for (int i = tid * 4; i < NN; i += NTHR * 4)
        *(float4*)(vals + i) = *(const float4*)(x + i);

    // ---- prefetch layer-0 edge quads into registers (plain cached) ----
    const size_t e0 = (size_t)b * EPB + (size_t)tid * 4;
    int4   s4 = *(const int4*)(edge_src + e0);
    int4   d4 = *(const int4*)(edge_dst + e0);
    float4 w4 = *(const float4*)(edge_w + e0);

    float* const prow = partials + (size_t)b * NN;

    for (int l = 0; l < NL; ++l) {
        // zero private accumulator; barrier also covers vals staging
        for (int i = tid * 4; i < NN; i += NTHR * 4)
            *(float4*)(accs + i) = make_float4(0.f, 0.f, 0.f, 0.f);
        __syncthreads();

        // ---- scatter: gather from LDS vals, accumulate via LDS atomics ----
        atomicAdd(&accs[d4.x], vals[s4.x] * w4.x);
        atomicAdd(&accs[d4.y], vals[s4.y] * w4.y);
        atomicAdd(&accs[d4.z], vals[s4.z] * w4.z);
        atomicAdd(&accs[d4.w], vals[s4.w] * w4.w);

        // prefetch next layer's edge quads (latency hides under barrier)
        if (l + 1 < NL) {
            const size_t e = (size_t)(l + 1) * NE + (size_t)b * EPB + (size_t)tid * 4;
            s4 = *(const int4*)(edge_src + e);
            d4 = *(const int4*)(edge_dst + e);
            w4 = *(const float4*)(edge_w + e);
        }
        __syncthreads();   // all LDS atomics done

        // ---- partial-row write: 8 floats/thread via 2 x 16B SC1 stores ----
        {
            const int i = tid * 8;   // NTHR*8 == NN exactly: one pass
            st2_f4_sc(prow + i,     *(const f32x4*)(accs + i),
                      prow + i + 4, *(const f32x4*)(accs + i + 4));
        }

        grid_barrier(2 * l);           // all partial rows visible device-wide

        // ---- reduce: block owns neurons [b*32, b*32+32) ----
        {
            // phase 1: 1024 threads, each sums 2 of 256 rows for one f32x4 col
            const int c4 = tid & 7;      // f32x4 column within 32-neuron slice
            const int r  = tid >> 3;     // 0..127
            const float* p0 = partials + (size_t)r * NN + b * NPB + c4 * 4;
            const float* p1 = p0 + (size_t)128 * NN;
            f32x4 a, c;
            ld2_f4_sc(p0, p1, a, c);
            sred4[r][c4] = a + c;
            __syncthreads();
            // phase 2: 64 threads fold 128 rows -> 8
            if (tid < 64) {
                const int j = tid & 7, g = tid >> 3;
                f32x4 s = sred4[g * 16][j];
                #pragma unroll
                for (int k = 1; k < 16; ++k) s += sred4[g * 16 + k][j];
                sredb[g][j] = s;
            }
            __syncthreads();
            // phase 3: 8 threads fold 8 -> 1, lrelu, SC1 write accv slice
            if (tid < 8) {
                f32x4 t = sredb[0][tid];
                #pragma unroll
                for (int k = 1; k < 8; ++k) t += sredb[k][tid];
                t.x = lrelu(t.x); t.y = lrelu(t.y);
                t.z = lrelu(t.z); t.w = lrelu(t.w);
                st_f4_sc(accv + b * NPB + tid * 4, t);
            }
        }

        grid_barrier(2 * l + 1);       // accv complete device-wide

        // ---- reload activated vector into LDS (16B SC1 loads) ----
        {
            const int i = tid * 8;
            f32x4 a, c;
            ld2_f4_sc(accv + i, accv + i + 4, a, c);
            *(f32x4*)(vals + i)     = a;
            *(f32x4*)(vals + i + 4) = c;
        }
        // next iteration's zero-loop __syncthreads covers this staging
    }

    // ---- output layer: 512 edges/block into 16 LDS bins ----
    __syncthreads();       // vals (layer-15 activations) ready in LDS
    if (tid < NOUTC) bins[tid] = 0.f;
    __syncthreads();
    if (tid < OPB) {
        const int e = b * OPB + tid;
        atomicAdd(&bins[out_dst[e]], vals[out_src[e]] * out_w[e]);
    }
    __syncthreads();
    if (tid < NOUTC) st_f(outs + (size_t)b * NOUTC + tid, bins[tid]);
    grid_barrier(32);      // outs complete device-wide

    // ---- final: reduce 256x16, lrelu, softmax (block 0 only) ----
    if (b == 0) {
        if (tid < 256) {
            const int j = tid & 15, g = tid >> 4;
            float s = 0.f;
            #pragma unroll
            for (int r2 = 0; r2 < NBLK / 16; ++r2)
                s += ld_f(outs + (size_t)(g + r2 * 16) * NOUTC + j);
            red[g][j] = s;
        }
        __syncthreads();
        if (tid < NOUTC) {
            float t = 0.f;
            #pragma unroll
            for (int g2 = 0; g2 < 16; ++g2) t += red[g2][tid];
            float v = lrelu(t);
            float m = v;
            #pragma unroll
            for (int off = 8; off >= 1; off >>= 1)
                m = fmaxf(m, __shfl_xor(m, off, 64));
            const float e = __expf(v - m);
            float ss = e;
            #pragma unroll
            for (int off = 8; off >= 1; off >>= 1)
                ss += __shfl_xor(ss, off, 64);
            out[tid] = e / ss;
        }
    }
}

extern "C" void kernel_launch(void* const* d_in, const int* in_sizes, int n_in,
                              void* d_out, int out_size, void* d_ws, size_t ws_size,
                              hipStream_t stream) {
    const float* x        = (const float*)d_in[0];
    const float* edge_w   = (const float*)d_in[1];
    const float* out_w    = (const float*)d_in[2];
    const int*   edge_src = (const int*)d_in[3];
    const int*   edge_dst = (const int*)d_in[4];
    const int*   out_src  = (const int*)d_in[5];
    const int*   out_dst  = (const int*)d_in[6];

    float* partials = (float*)d_ws;                       // NBLK*NN floats (8 MB)
    float* accv     = partials + (size_t)NBLK * NN;       // NN floats
    float* outs     = accv + NN;                          // NBLK*NOUTC floats
    float* out      = (float*)d_out;

    void* args[] = {&x, &edge_w, &out_w, &edge_src, &edge_dst,
                    &out_src, &out_dst, &partials, &accv, &outs, &out};
    hipLaunchCooperativeKernel((void*)mega_kernel, dim3(NBLK), dim3(NTHR),
                               args, 0, stream);
}